// Round 3
// baseline (300.704 us; speedup 1.0000x reference)
//
#include <hip/hip_runtime.h>
#include <math.h>

#define L_SEQ 1024
#define DMODEL 512
#define NHEAD 8
#define NB 2

typedef __attribute__((ext_vector_type(8))) short bf8;
typedef __attribute__((ext_vector_type(4))) float f4;

__device__ __forceinline__ short f2bf(float f) {
    unsigned u = __float_as_uint(f);
    unsigned r = u + 0x7FFF + ((u >> 16) & 1);   // round-to-nearest-even
    return (short)(r >> 16);
}

// ---------------------------------------------------------------------------
// pack mask + tf1..5 into one u32 per (b,l,m):
// bit31 = mask, bits24-30 = tf1+1 (0 => padding), 18-23 = tf2, 12-17 = tf3,
// 6-11 = tf4, 0-5 = tf5
// ---------------------------------------------------------------------------
__global__ __launch_bounds__(256) void pack_tf_kernel(
    const int* __restrict__ mask,
    const int* __restrict__ tf1, const int* __restrict__ tf2,
    const int* __restrict__ tf3, const int* __restrict__ tf4,
    const int* __restrict__ tf5, unsigned* __restrict__ pk, int n4)
{
    int i = blockIdx.x * 256 + threadIdx.x;
    if (i >= n4) return;
    const int4 mk = ((const int4*)mask)[i];
    const int4 a1 = ((const int4*)tf1)[i];
    const int4 a2 = ((const int4*)tf2)[i];
    const int4 a3 = ((const int4*)tf3)[i];
    const int4 a4 = ((const int4*)tf4)[i];
    const int4 a5 = ((const int4*)tf5)[i];
    uint4 o;
#define PK(F) ((mk.F ? 0x80000000u : 0u) | ((unsigned)(a1.F + 1) << 24) \
               | ((unsigned)a2.F << 18) | ((unsigned)a3.F << 12)        \
               | ((unsigned)a4.F << 6) | (unsigned)a5.F)
    o.x = PK(x); o.y = PK(y); o.z = PK(z); o.w = PK(w);
#undef PK
    ((uint4*)pk)[i] = o;
}

// ---------------------------------------------------------------------------
// 512x512 fp32 W[k][n] -> bf16 Wt[n][k], 4 matrices via blockIdx.z
// ---------------------------------------------------------------------------
__global__ __launch_bounds__(256) void transpose_cast_kernel(
    const float* __restrict__ s0, const float* __restrict__ s1,
    const float* __restrict__ s2, const float* __restrict__ s3,
    short* __restrict__ d0, short* __restrict__ d1,
    short* __restrict__ d2, short* __restrict__ d3)
{
    const float* src; short* dst;
    switch (blockIdx.z) {
        case 0: src = s0; dst = d0; break;
        case 1: src = s1; dst = d1; break;
        case 2: src = s2; dst = d2; break;
        default: src = s3; dst = d3; break;
    }
    __shared__ float tile[32][33];
    const int tx = threadIdx.x, ty = threadIdx.y;
    const int x0 = blockIdx.x * 32, y0 = blockIdx.y * 32;
#pragma unroll
    for (int j = 0; j < 32; j += 8)
        tile[ty + j][tx] = src[(size_t)(y0 + ty + j) * 512 + x0 + tx];
    __syncthreads();
#pragma unroll
    for (int j = 0; j < 32; j += 8)
        dst[(size_t)(x0 + ty + j) * 512 + y0 + tx] = f2bf(tile[tx][ty + j]);
}

// ---------------------------------------------------------------------------
// Projection GEMMs, all 3 in one launch (z = 0:q, 1:k, 2:v).
// A read directly as fp32, converted to bf16 in-register (no cast pre-pass).
// Block = 128 thr = 2 waves; tile 32m x 32n. grid (16, 64, 3).
// z<2 writes natural bf16 [m][512]; z==2 writes vht[b][n][l] transposed.
// ---------------------------------------------------------------------------
__global__ __launch_bounds__(128) void proj_gemm_kernel(
    const float* __restrict__ q, const float* __restrict__ k,
    const float* __restrict__ v,
    const short* __restrict__ Wtq, const short* __restrict__ Wtk,
    const short* __restrict__ Wtv,
    const float* __restrict__ b_q, const float* __restrict__ b_k,
    const float* __restrict__ b_v,
    short* __restrict__ qh, short* __restrict__ kh, short* __restrict__ vht)
{
    const int z = blockIdx.z;
    const float* A    = (z == 0) ? q   : (z == 1) ? k   : v;
    const short* Bt   = (z == 0) ? Wtq : (z == 1) ? Wtk : Wtv;
    const float* bias = (z == 0) ? b_q : (z == 1) ? b_k : b_v;

    const int w = threadIdx.x >> 6, lane = threadIdx.x & 63;
    const int lr = lane & 15, lq = lane >> 4;
    const int m_base = blockIdx.y * 32 + w * 16;
    const int n_base = blockIdx.x * 32;

    f4 acc[2];
    const f4 zero = {0.f, 0.f, 0.f, 0.f};
    acc[0] = zero; acc[1] = zero;

    for (int k0 = 0; k0 < 512; k0 += 32) {
        const float* p = A + (size_t)(m_base + lr) * 512 + k0 + lq * 8;
        float4 f0 = *(const float4*)p;
        float4 f1 = *(const float4*)(p + 4);
        bf8 a;
        a[0] = f2bf(f0.x); a[1] = f2bf(f0.y); a[2] = f2bf(f0.z); a[3] = f2bf(f0.w);
        a[4] = f2bf(f1.x); a[5] = f2bf(f1.y); a[6] = f2bf(f1.z); a[7] = f2bf(f1.w);
#pragma unroll
        for (int nf = 0; nf < 2; ++nf) {
            bf8 b = *(const bf8*)(Bt + (size_t)(n_base + nf * 16 + lr) * 512 + k0 + lq * 8);
            acc[nf] = __builtin_amdgcn_mfma_f32_16x16x32_bf16(a, b, acc[nf], 0, 0, 0);
        }
    }

    short* Cnat = (z == 0) ? qh : kh;
#pragma unroll
    for (int nf = 0; nf < 2; ++nf) {
        const int n = n_base + nf * 16 + lr;
        const float bv = bias[n];
        const int mrow = m_base + lq * 4;
#pragma unroll
        for (int r = 0; r < 4; ++r) {
            const float val = acc[nf][r] + bv;
            const int m = mrow + r;
            if (z < 2) {
                Cnat[(size_t)m * 512 + n] = f2bf(val);
            } else {
                const int bb = m >> 10, l = m & 1023;
                vht[((size_t)bb * 512 + n) * 1024 + l] = f2bf(val);
            }
        }
    }
}

// ---------------------------------------------------------------------------
// Fused flash attention: QK^T + bias + mask + softmax + attn-write + PV.
// Two-pass (max/sum, then normalize+PV), no score materialization.
// Block = (z, 32 q-rows): 512 thr = 8 waves = 2 row-groups (wr) x 4 m-quarters
// (wm). Each wave: 16 rows x 256 m (4 tiles of 64), K=64 QK^T, PV over vht.
// grid (16 z, 32 lt). attn written once (normalized fp32); pv bf16.
// ---------------------------------------------------------------------------
__global__ __launch_bounds__(512) void flash_attn_kernel(
    const short* __restrict__ qh, const short* __restrict__ kh,
    const short* __restrict__ vht, const unsigned* __restrict__ pk,
    const float* __restrict__ emb1, const float* __restrict__ emb2,
    const float* __restrict__ emb3, const float* __restrict__ emb4,
    const float* __restrict__ emb5,
    float* __restrict__ attn, short* __restrict__ pv)
{
    const int z = blockIdx.x, h = z >> 1, b = z & 1;
    const int t = threadIdx.x;
    const int wave = t >> 6, lane = t & 63;
    const int wr = wave & 1, wm = wave >> 1;
    const int lr = lane & 15, lq = lane >> 4;
    const int l0 = blockIdx.y * 32 + wr * 16;
    const int mbase = wm * 256;

    __shared__ float embs[5][64];
    __shared__ float red_mx[4][2][16];
    __shared__ float red_sm[4][2][16];
    __shared__ short plds[8][1024];          // per-wave 16x64 bf16 P tile (swizzled)
    __shared__ float ored[4][2][16][64];     // PV partials [wm][wr][row][d]

    if (t < 320) {
        const float* es[5] = {emb1, emb2, emb3, emb4, emb5};
        embs[t >> 6][t & 63] = es[t >> 6][(t & 63) * NHEAD + h];
    }

    // Q fragments (A-operand: lane lr = row, lq*8 = k offset) — loaded once
    const short* qp = qh + ((size_t)(b * L_SEQ + l0 + lr)) * DMODEL + h * 64 + lq * 8;
    const bf8 aq0 = *(const bf8*)qp;
    const bf8 aq1 = *(const bf8*)(qp + 32);

    const int lrow0 = l0 + lq * 4;           // first of this lane's 4 C/D rows
    int tboff[4];
#pragma unroll
    for (int r = 0; r < 4; ++r)
        tboff[r] = (b * L_SEQ + lrow0 + r) * L_SEQ + lr;
    const short* kbp = kh + (size_t)b * L_SEQ * DMODEL + h * 64 + lq * 8;

    __syncthreads();

    const f4 zero = {0.f, 0.f, 0.f, 0.f};

    // S-tile compute: MFMA (verified scores mapping) + packed bias/mask fold
#define COMPUTE_S(m0, sv)                                                     \
    {                                                                         \
        f4 acc[4];                                                            \
        acc[0] = zero; acc[1] = zero; acc[2] = zero; acc[3] = zero;           \
        _Pragma("unroll")                                                     \
        for (int nt = 0; nt < 4; ++nt) {                                      \
            const short* kp = kbp + (size_t)((m0) + nt * 16 + lr) * DMODEL;   \
            bf8 b0 = *(const bf8*)kp;                                         \
            bf8 b1 = *(const bf8*)(kp + 32);                                  \
            acc[nt] = __builtin_amdgcn_mfma_f32_16x16x32_bf16(aq0, b0, acc[nt], 0, 0, 0); \
            acc[nt] = __builtin_amdgcn_mfma_f32_16x16x32_bf16(aq1, b1, acc[nt], 0, 0, 0); \
        }                                                                     \
        _Pragma("unroll")                                                     \
        for (int nt = 0; nt < 4; ++nt) {                                      \
            _Pragma("unroll")                                                 \
            for (int r = 0; r < 4; ++r) {                                     \
                const unsigned u = pk[tboff[r] + (m0) + nt * 16];             \
                float sval;                                                   \
                if (u & 0x80000000u) { sval = -INFINITY; }                    \
                else {                                                        \
                    const int i1m = (u >> 24) & 0x7F;                         \
                    float bs = 0.f;                                           \
                    if (i1m) bs = embs[0][i1m - 1] + embs[1][(u >> 18) & 63]  \
                                + embs[2][(u >> 12) & 63]                     \
                                + embs[3][(u >> 6) & 63] + embs[4][u & 63];   \
                    sval = (acc[nt][r] + bs) * 0.125f;                        \
                }                                                             \
                sv[nt][r] = sval;                                             \
            }                                                                 \
        }                                                                     \
    }

    // ---- pass 1: per-row online max + sum over this wave's m-range ----
    float mx[4], sm[4];
#pragma unroll
    for (int r = 0; r < 4; ++r) { mx[r] = -INFINITY; sm[r] = 0.f; }

    for (int mt = 0; mt < 4; ++mt) {
        const int m0 = mbase + mt * 64;
        float sv[4][4];
        COMPUTE_S(m0, sv);
        float tmx[4];
#pragma unroll
        for (int r = 0; r < 4; ++r)
            tmx[r] = fmaxf(fmaxf(sv[0][r], sv[1][r]), fmaxf(sv[2][r], sv[3][r]));
#pragma unroll
        for (int r = 0; r < 4; ++r) {
#pragma unroll
            for (int off = 1; off < 16; off <<= 1)
                tmx[r] = fmaxf(tmx[r], __shfl_xor(tmx[r], off));
        }
        float mnew[4], tsum[4];
#pragma unroll
        for (int r = 0; r < 4; ++r) { mnew[r] = fmaxf(mx[r], tmx[r]); tsum[r] = 0.f; }
#pragma unroll
        for (int nt = 0; nt < 4; ++nt)
#pragma unroll
            for (int r = 0; r < 4; ++r)
                tsum[r] += (sv[nt][r] > -INFINITY) ? __expf(sv[nt][r] - mnew[r]) : 0.f;
#pragma unroll
        for (int r = 0; r < 4; ++r) {
#pragma unroll
            for (int off = 1; off < 16; off <<= 1)
                tsum[r] += __shfl_xor(tsum[r], off);
        }
#pragma unroll
        for (int r = 0; r < 4; ++r) {
            const float fac = (mx[r] == -INFINITY) ? 0.f : __expf(mx[r] - mnew[r]);
            sm[r] = sm[r] * fac + tsum[r];
            mx[r] = mnew[r];
        }
    }

    // combine across the 4 m-quarters
    if (lr == 0) {
#pragma unroll
        for (int r = 0; r < 4; ++r) {
            red_mx[wm][wr][lq * 4 + r] = mx[r];
            red_sm[wm][wr][lq * 4 + r] = sm[r];
        }
    }
    __syncthreads();

    float mfin[4], inv[4];
#pragma unroll
    for (int r = 0; r < 4; ++r) {
        const int row = lq * 4 + r;
        const float m0_ = red_mx[0][wr][row], m1_ = red_mx[1][wr][row];
        const float m2_ = red_mx[2][wr][row], m3_ = red_mx[3][wr][row];
        const float mf = fmaxf(fmaxf(m0_, m1_), fmaxf(m2_, m3_));
        float s = 0.f;
        if (m0_ > -INFINITY) s += red_sm[0][wr][row] * __expf(m0_ - mf);
        if (m1_ > -INFINITY) s += red_sm[1][wr][row] * __expf(m1_ - mf);
        if (m2_ > -INFINITY) s += red_sm[2][wr][row] * __expf(m2_ - mf);
        if (m3_ > -INFINITY) s += red_sm[3][wr][row] * __expf(m3_ - mf);
        mfin[r] = mf;
        inv[r] = 1.0f / s;
    }

    // ---- pass 2: recompute, normalize, write attn, PV-accumulate ----
    f4 oacc[4];
    oacc[0] = zero; oacc[1] = zero; oacc[2] = zero; oacc[3] = zero;
    float* ap = attn + (size_t)z * L_SEQ * L_SEQ;
    short* pbase = &plds[wave][0];

    for (int mt = 0; mt < 4; ++mt) {
        const int m0 = mbase + mt * 64;
        float sv[4][4];
        COMPUTE_S(m0, sv);
#pragma unroll
        for (int nt = 0; nt < 4; ++nt) {
#pragma unroll
            for (int r = 0; r < 4; ++r) {
                const float p = (sv[nt][r] > -INFINITY)
                                    ? __expf(sv[nt][r] - mfin[r]) * inv[r] : 0.f;
                ap[(size_t)(lrow0 + r) * L_SEQ + m0 + nt * 16 + lr] = p;
                const int row = lq * 4 + r, col = nt * 16 + lr;
                const int boff = (row * 128 + col * 2) ^ ((row & 7) << 4);
                *(short*)((char*)pbase + boff) = f2bf(p);
            }
        }
        asm volatile("s_waitcnt lgkmcnt(0)" ::: "memory");
#pragma unroll
        for (int kk = 0; kk < 2; ++kk) {
            const int rb = (lr * 128 + (kk * 32 + lq * 8) * 2) ^ ((lr & 7) << 4);
            const bf8 pa = *(const bf8*)((const char*)pbase + rb);
#pragma unroll
            for (int ntd = 0; ntd < 4; ++ntd) {
                const bf8 bv = *(const bf8*)(vht
                    + ((size_t)b * DMODEL + h * 64 + ntd * 16 + lr) * L_SEQ
                    + m0 + kk * 32 + lq * 8);
                oacc[ntd] = __builtin_amdgcn_mfma_f32_16x16x32_bf16(pa, bv, oacc[ntd], 0, 0, 0);
            }
        }
    }
#undef COMPUTE_S

    // ---- PV cross-quarter reduce + store ----
#pragma unroll
    for (int ntd = 0; ntd < 4; ++ntd)
#pragma unroll
        for (int r = 0; r < 4; ++r)
            ored[wm][wr][lq * 4 + r][ntd * 16 + lr] = oacc[ntd][r];
    __syncthreads();
    if (wm == 0) {
#pragma unroll
        for (int ntd = 0; ntd < 4; ++ntd) {
#pragma unroll
            for (int r = 0; r < 4; ++r) {
                const int row = lq * 4 + r;
                const float s = ored[0][wr][row][ntd * 16 + lr]
                              + ored[1][wr][row][ntd * 16 + lr]
                              + ored[2][wr][row][ntd * 16 + lr]
                              + ored[3][wr][row][ntd * 16 + lr];
                pv[((size_t)(b * L_SEQ) + l0 + row) * 512 + h * 64 + ntd * 16 + lr] = f2bf(s);
            }
        }
    }
}

// ---------------------------------------------------------------------------
// FC GEMM: C[m,n] = sum_k pv[m,k]*Wtfc[n,k] + fc_b[n], fp32 out (to d_out).
// ---------------------------------------------------------------------------
__global__ __launch_bounds__(128) void fc_gemm_kernel(
    const short* __restrict__ A, const short* __restrict__ Bt,
    const float* __restrict__ bias, float* __restrict__ Cout)
{
    const int w = threadIdx.x >> 6, lane = threadIdx.x & 63;
    const int lr = lane & 15, lq = lane >> 4;
    const int m_base = blockIdx.y * 32 + w * 16;
    const int n_base = blockIdx.x * 32;

    f4 acc[2];
    const f4 zero = {0.f, 0.f, 0.f, 0.f};
    acc[0] = zero; acc[1] = zero;

    for (int k0 = 0; k0 < 512; k0 += 32) {
        bf8 a = *(const bf8*)(A + (size_t)(m_base + lr) * 512 + k0 + lq * 8);
#pragma unroll
        for (int nf = 0; nf < 2; ++nf) {
            bf8 b = *(const bf8*)(Bt + (size_t)(n_base + nf * 16 + lr) * 512 + k0 + lq * 8);
            acc[nf] = __builtin_amdgcn_mfma_f32_16x16x32_bf16(a, b, acc[nf], 0, 0, 0);
        }
    }

#pragma unroll
    for (int nf = 0; nf < 2; ++nf) {
        const int n = n_base + nf * 16 + lr;
        const float bv = bias[n];
        const int mrow = m_base + lq * 4;
#pragma unroll
        for (int r = 0; r < 4; ++r)
            Cout[(size_t)(mrow + r) * 512 + n] = acc[nf][r] + bv;
    }
}

// ---------------------------------------------------------------------------
// residual add + LayerNorm, one block per row, in-place on x(=out)
// ---------------------------------------------------------------------------
__global__ __launch_bounds__(256) void ln_kernel(
    const float* __restrict__ x, const float* __restrict__ res,
    const float* __restrict__ g, const float* __restrict__ bvec,
    float* __restrict__ out)
{
    const int row = blockIdx.x;
    const int t = threadIdx.x;
    float2 xv = ((const float2*)(x + (size_t)row * DMODEL))[t];
    float2 rv = ((const float2*)(res + (size_t)row * DMODEL))[t];
    const float a = xv.x + rv.x;
    const float c = xv.y + rv.y;
    float s = a + c, sq = a * a + c * c;
#pragma unroll
    for (int off = 32; off; off >>= 1) {
        s  += __shfl_down(s, off);
        sq += __shfl_down(sq, off);
    }
    __shared__ float ssum[4], ssq[4];
    __shared__ float smu, srs;
    const int wid = t >> 6, lane = t & 63;
    if (lane == 0) { ssum[wid] = s; ssq[wid] = sq; }
    __syncthreads();
    if (t == 0) {
        float ts = ssum[0] + ssum[1] + ssum[2] + ssum[3];
        float tq = ssq[0] + ssq[1] + ssq[2] + ssq[3];
        float mu = ts * (1.0f / DMODEL);
        float var = tq * (1.0f / DMODEL) - mu * mu;
        smu = mu;
        srs = rsqrtf(var + 1e-5f);
    }
    __syncthreads();
    const float mu = smu, rs = srs;
    float2 gv = ((const float2*)g)[t];
    float2 bv = ((const float2*)bvec)[t];
    float2 o;
    o.x = (a - mu) * rs * gv.x + bv.x;
    o.y = (c - mu) * rs * gv.y + bv.y;
    ((float2*)(out + (size_t)row * DMODEL))[t] = o;
}

extern "C" void kernel_launch(void* const* d_in, const int* in_sizes, int n_in,
                              void* d_out, int out_size, void* d_ws, size_t ws_size,
                              hipStream_t stream)
{
    const float* q    = (const float*)d_in[0];
    const float* k    = (const float*)d_in[1];
    const float* v    = (const float*)d_in[2];
    const int*   mask = (const int*)d_in[3];
    const int*   tf1  = (const int*)d_in[4];
    const int*   tf2  = (const int*)d_in[5];
    const int*   tf3  = (const int*)d_in[6];
    const int*   tf4  = (const int*)d_in[7];
    const int*   tf5  = (const int*)d_in[8];
    const float* w_q  = (const float*)d_in[9];
    const float* b_q  = (const float*)d_in[10];
    const float* w_k  = (const float*)d_in[11];
    const float* b_k  = (const float*)d_in[12];
    const float* w_v  = (const float*)d_in[13];
    const float* b_v  = (const float*)d_in[14];
    const float* emb1 = (const float*)d_in[15];
    const float* emb2 = (const float*)d_in[16];
    const float* emb3 = (const float*)d_in[17];
    const float* emb4 = (const float*)d_in[18];
    const float* emb5 = (const float*)d_in[19];
    const float* fc_w = (const float*)d_in[20];
    const float* fc_b = (const float*)d_in[21];
    const float* ln_g = (const float*)d_in[22];
    const float* ln_b = (const float*)d_in[23];

    float* out  = (float*)d_out;                       // [2048][512]
    float* attn = out + (size_t)NB * L_SEQ * DMODEL;   // [16][1024][1024]

    // ws layout (bytes): total 18 MiB of the 20 MiB workspace
    char* wsb = (char*)d_ws;
    unsigned* pk = (unsigned*)(wsb + 0);                // 8 MiB [2][1024][1024] u32
    short* Wtq  = (short*)(wsb + (8u << 20));           // 0.5 MiB [512n][512k]
    short* Wtk  = (short*)(wsb + (8u << 20) + (512u << 10));
    short* Wtv  = (short*)(wsb + (9u << 20));
    short* Wtfc = (short*)(wsb + (9u << 20) + (512u << 10));
    short* qh   = (short*)(wsb + (10u << 20));          // 2 MiB [2048][512] bf16
    short* kh   = (short*)(wsb + (12u << 20));          // 2 MiB
    short* vht  = (short*)(wsb + (14u << 20));          // 2 MiB [2][512][1024] bf16
    short* pv   = (short*)(wsb + (16u << 20));          // 2 MiB [2048][512] bf16

    const int npk4 = NB * L_SEQ * L_SEQ / 4;            // 524288

    pack_tf_kernel<<<npk4 / 256, 256, 0, stream>>>(
        mask, tf1, tf2, tf3, tf4, tf5, pk, npk4);

    transpose_cast_kernel<<<dim3(16, 16, 4), dim3(32, 8), 0, stream>>>(
        w_q, w_k, w_v, fc_w, Wtq, Wtk, Wtv, Wtfc);

    proj_gemm_kernel<<<dim3(16, 64, 3), 128, 0, stream>>>(
        q, k, v, Wtq, Wtk, Wtv, b_q, b_k, b_v, qh, kh, vht);

    flash_attn_kernel<<<dim3(16, 32), 512, 0, stream>>>(
        qh, kh, vht, pk, emb1, emb2, emb3, emb4, emb5, attn, pv);

    fc_gemm_kernel<<<dim3(16, 64), 128, 0, stream>>>(pv, Wtfc, fc_b, out);

    ln_kernel<<<NB * L_SEQ, 256, 0, stream>>>(out, q, ln_g, ln_b, out);
}

// Round 4
// 278.086 us; speedup vs baseline: 1.0813x; 1.0813x over previous
//
#include <hip/hip_runtime.h>
#include <math.h>

#define L_SEQ 1024
#define DMODEL 512
#define NHEAD 8
#define NB 2

typedef __attribute__((ext_vector_type(8))) short bf8;
typedef __attribute__((ext_vector_type(4))) float f4;

__device__ __forceinline__ short f2bf(float f) {
    unsigned u = __float_as_uint(f);
    unsigned r = u + 0x7FFF + ((u >> 16) & 1);   // round-to-nearest-even
    return (short)(r >> 16);
}

// ---------------------------------------------------------------------------
// pack mask + tf1..5 into one u32 per (b,l,m):
// bit31 = mask, bits24-30 = tf1+1 (0 => padding), 18-23 = tf2, 12-17 = tf3,
// 6-11 = tf4, 0-5 = tf5
// ---------------------------------------------------------------------------
__global__ __launch_bounds__(256) void pack_tf_kernel(
    const int* __restrict__ mask,
    const int* __restrict__ tf1, const int* __restrict__ tf2,
    const int* __restrict__ tf3, const int* __restrict__ tf4,
    const int* __restrict__ tf5, unsigned* __restrict__ pk, int n4)
{
    int i = blockIdx.x * 256 + threadIdx.x;
    if (i >= n4) return;
    const int4 mk = ((const int4*)mask)[i];
    const int4 a1 = ((const int4*)tf1)[i];
    const int4 a2 = ((const int4*)tf2)[i];
    const int4 a3 = ((const int4*)tf3)[i];
    const int4 a4 = ((const int4*)tf4)[i];
    const int4 a5 = ((const int4*)tf5)[i];
    uint4 o;
#define PK(F) ((mk.F ? 0x80000000u : 0u) | ((unsigned)(a1.F + 1) << 24) \
               | ((unsigned)a2.F << 18) | ((unsigned)a3.F << 12)        \
               | ((unsigned)a4.F << 6) | (unsigned)a5.F)
    o.x = PK(x); o.y = PK(y); o.z = PK(z); o.w = PK(w);
#undef PK
    ((uint4*)pk)[i] = o;
}

// ---------------------------------------------------------------------------
// 512x512 fp32 W[k][n] -> bf16 Wt[n][k], 4 matrices via blockIdx.z
// ---------------------------------------------------------------------------
__global__ __launch_bounds__(256) void transpose_cast_kernel(
    const float* __restrict__ s0, const float* __restrict__ s1,
    const float* __restrict__ s2, const float* __restrict__ s3,
    short* __restrict__ d0, short* __restrict__ d1,
    short* __restrict__ d2, short* __restrict__ d3)
{
    const float* src; short* dst;
    switch (blockIdx.z) {
        case 0: src = s0; dst = d0; break;
        case 1: src = s1; dst = d1; break;
        case 2: src = s2; dst = d2; break;
        default: src = s3; dst = d3; break;
    }
    __shared__ float tile[32][33];
    const int tx = threadIdx.x, ty = threadIdx.y;
    const int x0 = blockIdx.x * 32, y0 = blockIdx.y * 32;
#pragma unroll
    for (int j = 0; j < 32; j += 8)
        tile[ty + j][tx] = src[(size_t)(y0 + ty + j) * 512 + x0 + tx];
    __syncthreads();
#pragma unroll
    for (int j = 0; j < 32; j += 8)
        dst[(size_t)(x0 + ty + j) * 512 + y0 + tx] = f2bf(tile[tx][ty + j]);
}

// ---------------------------------------------------------------------------
// Projection GEMMs, all 3 in one launch (z = 0:q, 1:k, 2:v).
// A read directly as fp32, converted to bf16 in-register.
// z<2 writes natural bf16 [m][512]; z==2 writes vht[b][n][l] transposed.
// ---------------------------------------------------------------------------
__global__ __launch_bounds__(128) void proj_gemm_kernel(
    const float* __restrict__ q, const float* __restrict__ k,
    const float* __restrict__ v,
    const short* __restrict__ Wtq, const short* __restrict__ Wtk,
    const short* __restrict__ Wtv,
    const float* __restrict__ b_q, const float* __restrict__ b_k,
    const float* __restrict__ b_v,
    short* __restrict__ qh, short* __restrict__ kh, short* __restrict__ vht)
{
    const int z = blockIdx.z;
    const float* A    = (z == 0) ? q   : (z == 1) ? k   : v;
    const short* Bt   = (z == 0) ? Wtq : (z == 1) ? Wtk : Wtv;
    const float* bias = (z == 0) ? b_q : (z == 1) ? b_k : b_v;

    const int w = threadIdx.x >> 6, lane = threadIdx.x & 63;
    const int lr = lane & 15, lq = lane >> 4;
    const int m_base = blockIdx.y * 32 + w * 16;
    const int n_base = blockIdx.x * 32;

    f4 acc[2];
    const f4 zero = {0.f, 0.f, 0.f, 0.f};
    acc[0] = zero; acc[1] = zero;

    for (int k0 = 0; k0 < 512; k0 += 32) {
        const float* p = A + (size_t)(m_base + lr) * 512 + k0 + lq * 8;
        float4 f0 = *(const float4*)p;
        float4 f1 = *(const float4*)(p + 4);
        bf8 a;
        a[0] = f2bf(f0.x); a[1] = f2bf(f0.y); a[2] = f2bf(f0.z); a[3] = f2bf(f0.w);
        a[4] = f2bf(f1.x); a[5] = f2bf(f1.y); a[6] = f2bf(f1.z); a[7] = f2bf(f1.w);
#pragma unroll
        for (int nf = 0; nf < 2; ++nf) {
            bf8 b = *(const bf8*)(Bt + (size_t)(n_base + nf * 16 + lr) * 512 + k0 + lq * 8);
            acc[nf] = __builtin_amdgcn_mfma_f32_16x16x32_bf16(a, b, acc[nf], 0, 0, 0);
        }
    }

    short* Cnat = (z == 0) ? qh : kh;
#pragma unroll
    for (int nf = 0; nf < 2; ++nf) {
        const int n = n_base + nf * 16 + lr;
        const float bv = bias[n];
        const int mrow = m_base + lq * 4;
#pragma unroll
        for (int r = 0; r < 4; ++r) {
            const float val = acc[nf][r] + bv;
            const int m = mrow + r;
            if (z < 2) {
                Cnat[(size_t)m * 512 + n] = f2bf(val);
            } else {
                const int bb = m >> 10, l = m & 1023;
                vht[((size_t)bb * 512 + n) * 1024 + l] = f2bf(val);
            }
        }
    }
}

// ---------------------------------------------------------------------------
// Fused scores + bias + mask + softmax (single pass), writes normalized attn.
// Block = (z, 16 q-rows), 256 thr = 4 waves; wave w owns m-quarter w*256.
// Full S-quarter held in registers (sv[16][4]); one QK^T, one exp pass.
// S mapping + pk bias fold identical to the verified flash kernel.
// ---------------------------------------------------------------------------
__global__ __launch_bounds__(256) void ssm_kernel(
    const short* __restrict__ qh, const short* __restrict__ kh,
    const unsigned* __restrict__ pk,
    const float* __restrict__ emb1, const float* __restrict__ emb2,
    const float* __restrict__ emb3, const float* __restrict__ emb4,
    const float* __restrict__ emb5,
    float* __restrict__ attn)
{
    const int z = blockIdx.x, h = z >> 1, b = z & 1;
    const int t = threadIdx.x;
    const int wave = t >> 6, lane = t & 63;
    const int lr = lane & 15, lq = lane >> 4;
    const int l0 = blockIdx.y * 16;
    const int mbase = wave * 256;

    __shared__ float embs[5][64];
    __shared__ float red_mx[4][16];
    __shared__ float red_sm[4][16];

    {
        const float* es[5] = {emb1, emb2, emb3, emb4, emb5};
        for (int i = t; i < 320; i += 256)
            embs[i >> 6][i & 63] = es[i >> 6][(i & 63) * NHEAD + h];
    }

    // Q fragments (A-operand: lane lr = row, lq*8 = k offset) — loaded once
    const short* qp = qh + ((size_t)(b * L_SEQ + l0 + lr)) * DMODEL + h * 64 + lq * 8;
    const bf8 aq0 = *(const bf8*)qp;
    const bf8 aq1 = *(const bf8*)(qp + 32);

    const int lrow0 = l0 + lq * 4;           // first of this lane's 4 C/D rows
    int tboff[4];
#pragma unroll
    for (int r = 0; r < 4; ++r)
        tboff[r] = (b * L_SEQ + lrow0 + r) * L_SEQ + lr;
    const short* kbp = kh + (size_t)b * L_SEQ * DMODEL + h * 64 + lq * 8;

    __syncthreads();

    const f4 zero = {0.f, 0.f, 0.f, 0.f};

    // ---- compute raw S for all 16 m-tiles of this wave's quarter ----
    float sv[16][4];
#pragma unroll
    for (int tile = 0; tile < 16; ++tile) {
        const int m0 = mbase + tile * 16;
        f4 acc = zero;
        const short* kp = kbp + (size_t)(m0 + lr) * DMODEL;
        const bf8 b0 = *(const bf8*)kp;
        const bf8 b1 = *(const bf8*)(kp + 32);
        acc = __builtin_amdgcn_mfma_f32_16x16x32_bf16(aq0, b0, acc, 0, 0, 0);
        acc = __builtin_amdgcn_mfma_f32_16x16x32_bf16(aq1, b1, acc, 0, 0, 0);
#pragma unroll
        for (int r = 0; r < 4; ++r) {
            const unsigned u = pk[tboff[r] + m0];
            float sval;
            if (u & 0x80000000u) { sval = -INFINITY; }
            else {
                const int i1m = (u >> 24) & 0x7F;
                float bs = 0.f;
                if (i1m) bs = embs[0][i1m - 1] + embs[1][(u >> 18) & 63]
                            + embs[2][(u >> 12) & 63]
                            + embs[3][(u >> 6) & 63] + embs[4][u & 63];
                sval = (acc[r] + bs) * 0.125f;
            }
            sv[tile][r] = sval;
        }
    }

    // ---- per-row max: in-lane over tiles -> 16-lane shfl -> cross-wave LDS ----
    float mx[4];
#pragma unroll
    for (int r = 0; r < 4; ++r) mx[r] = -INFINITY;
#pragma unroll
    for (int tile = 0; tile < 16; ++tile)
#pragma unroll
        for (int r = 0; r < 4; ++r) mx[r] = fmaxf(mx[r], sv[tile][r]);
#pragma unroll
    for (int r = 0; r < 4; ++r) {
#pragma unroll
        for (int off = 1; off < 16; off <<= 1)
            mx[r] = fmaxf(mx[r], __shfl_xor(mx[r], off));
    }
    if (lr == 0) {
#pragma unroll
        for (int r = 0; r < 4; ++r) red_mx[wave][lq * 4 + r] = mx[r];
    }
    __syncthreads();

    float mf[4];
#pragma unroll
    for (int r = 0; r < 4; ++r) {
        const int row = lq * 4 + r;
        mf[r] = fmaxf(fmaxf(red_mx[0][row], red_mx[1][row]),
                      fmaxf(red_mx[2][row], red_mx[3][row]));
    }

    // ---- exp (once) + per-row sum ----
    float sm[4] = {0.f, 0.f, 0.f, 0.f};
#pragma unroll
    for (int tile = 0; tile < 16; ++tile) {
#pragma unroll
        for (int r = 0; r < 4; ++r) {
            const float e = (sv[tile][r] > -INFINITY) ? __expf(sv[tile][r] - mf[r]) : 0.f;
            sv[tile][r] = e;
            sm[r] += e;
        }
    }
#pragma unroll
    for (int r = 0; r < 4; ++r) {
#pragma unroll
        for (int off = 1; off < 16; off <<= 1)
            sm[r] += __shfl_xor(sm[r], off);
    }
    if (lr == 0) {
#pragma unroll
        for (int r = 0; r < 4; ++r) red_sm[wave][lq * 4 + r] = sm[r];
    }
    __syncthreads();

    float inv[4];
#pragma unroll
    for (int r = 0; r < 4; ++r) {
        const int row = lq * 4 + r;
        const float s = (red_sm[0][row] + red_sm[1][row])
                      + (red_sm[2][row] + red_sm[3][row]);
        inv[r] = (s > 0.f) ? 1.0f / s : 0.f;
    }

    // ---- normalize + write attn ----
    float* ap = attn + (size_t)z * L_SEQ * L_SEQ;
#pragma unroll
    for (int tile = 0; tile < 16; ++tile) {
#pragma unroll
        for (int r = 0; r < 4; ++r)
            ap[(size_t)(lrow0 + r) * L_SEQ + mbase + tile * 16 + lr] = sv[tile][r] * inv[r];
    }
}

// ---------------------------------------------------------------------------
// AV GEMM, split-K: per z=h*2+b, pv[b,l,h*64+d] = sum_m attn[z,l,m]*vht[b,h*64+d,m]
// Block = 16 rows x 64 d; each of 4 waves owns a 256-wide K-quarter, then
// cross-wave LDS reduce (wave w finalizes cols w*16..w*16+15).
// ---------------------------------------------------------------------------
__global__ __launch_bounds__(256) void av_mfma_kernel(
    const float* __restrict__ attn, const short* __restrict__ vht,
    short* __restrict__ pv)
{
    const int z = blockIdx.y, h = z >> 1, b = z & 1;
    const int w = threadIdx.x >> 6, lane = threadIdx.x & 63;
    const int lr = lane & 15, lq = lane >> 4;
    const int l0 = blockIdx.x * 16;
    const float* Ab = attn + (size_t)z * L_SEQ * L_SEQ;
    const short* Bb = vht + ((size_t)b * 512 + h * 64) * 1024;

    f4 acc[4];
    const f4 zero = {0.f, 0.f, 0.f, 0.f};
#pragma unroll
    for (int nt = 0; nt < 4; ++nt) acc[nt] = zero;

    const int kbeg = w * 256;
    for (int k0 = kbeg; k0 < kbeg + 256; k0 += 32) {
        const float* p = Ab + (size_t)(l0 + lr) * 1024 + k0 + lq * 8;
        float4 f0 = *(const float4*)p;
        float4 f1 = *(const float4*)(p + 4);
        bf8 a;
        a[0] = f2bf(f0.x); a[1] = f2bf(f0.y); a[2] = f2bf(f0.z); a[3] = f2bf(f0.w);
        a[4] = f2bf(f1.x); a[5] = f2bf(f1.y); a[6] = f2bf(f1.z); a[7] = f2bf(f1.w);
#pragma unroll
        for (int nt = 0; nt < 4; ++nt) {
            bf8 bv = *(const bf8*)(Bb + (size_t)(nt * 16 + lr) * 1024 + k0 + lq * 8);
            acc[nt] = __builtin_amdgcn_mfma_f32_16x16x32_bf16(a, bv, acc[nt], 0, 0, 0);
        }
    }

    // cross-wave reduce: red[wave][nt][row][col], padded to 17 for bank spread
    __shared__ float red[4][4][16][17];
#pragma unroll
    for (int nt = 0; nt < 4; ++nt)
#pragma unroll
        for (int r = 0; r < 4; ++r)
            red[w][nt][lq * 4 + r][lr] = acc[nt][r];
    __syncthreads();

    // wave w finalizes n-frag nt == w
    f4 sum = zero;
#pragma unroll
    for (int j = 0; j < 4; ++j)
#pragma unroll
        for (int r = 0; r < 4; ++r)
            sum[r] += red[j][w][lq * 4 + r][lr];

#pragma unroll
    for (int r = 0; r < 4; ++r)
        pv[(size_t)(b * L_SEQ + l0 + lq * 4 + r) * 512 + h * 64 + w * 16 + lr] = f2bf(sum[r]);
}

// ---------------------------------------------------------------------------
// FC GEMM: C[m,n] = sum_k pv[m,k]*Wtfc[n,k] + fc_b[n], fp32 out (to d_out).
// ---------------------------------------------------------------------------
__global__ __launch_bounds__(128) void fc_gemm_kernel(
    const short* __restrict__ A, const short* __restrict__ Bt,
    const float* __restrict__ bias, float* __restrict__ Cout)
{
    const int w = threadIdx.x >> 6, lane = threadIdx.x & 63;
    const int lr = lane & 15, lq = lane >> 4;
    const int m_base = blockIdx.y * 32 + w * 16;
    const int n_base = blockIdx.x * 32;

    f4 acc[2];
    const f4 zero = {0.f, 0.f, 0.f, 0.f};
    acc[0] = zero; acc[1] = zero;

    for (int k0 = 0; k0 < 512; k0 += 32) {
        bf8 a = *(const bf8*)(A + (size_t)(m_base + lr) * 512 + k0 + lq * 8);
#pragma unroll
        for (int nf = 0; nf < 2; ++nf) {
            bf8 b = *(const bf8*)(Bt + (size_t)(n_base + nf * 16 + lr) * 512 + k0 + lq * 8);
            acc[nf] = __builtin_amdgcn_mfma_f32_16x16x32_bf16(a, b, acc[nf], 0, 0, 0);
        }
    }

#pragma unroll
    for (int nf = 0; nf < 2; ++nf) {
        const int n = n_base + nf * 16 + lr;
        const float bv = bias[n];
        const int mrow = m_base + lq * 4;
#pragma unroll
        for (int r = 0; r < 4; ++r)
            Cout[(size_t)(mrow + r) * 512 + n] = acc[nf][r] + bv;
    }
}

// ---------------------------------------------------------------------------
// residual add + LayerNorm, one block per row, in-place on x(=out)
// ---------------------------------------------------------------------------
__global__ __launch_bounds__(256) void ln_kernel(
    const float* __restrict__ x, const float* __restrict__ res,
    const float* __restrict__ g, const float* __restrict__ bvec,
    float* __restrict__ out)
{
    const int row = blockIdx.x;
    const int t = threadIdx.x;
    float2 xv = ((const float2*)(x + (size_t)row * DMODEL))[t];
    float2 rv = ((const float2*)(res + (size_t)row * DMODEL))[t];
    const float a = xv.x + rv.x;
    const float c = xv.y + rv.y;
    float s = a + c, sq = a * a + c * c;
#pragma unroll
    for (int off = 32; off; off >>= 1) {
        s  += __shfl_down(s, off);
        sq += __shfl_down(sq, off);
    }
    __shared__ float ssum[4], ssq[4];
    __shared__ float smu, srs;
    const int wid = t >> 6, lane = t & 63;
    if (lane == 0) { ssum[wid] = s; ssq[wid] = sq; }
    __syncthreads();
    if (t == 0) {
        float ts = ssum[0] + ssum[1] + ssum[2] + ssum[3];
        float tq = ssq[0] + ssq[1] + ssq[2] + ssq[3];
        float mu = ts * (1.0f / DMODEL);
        float var = tq * (1.0f / DMODEL) - mu * mu;
        smu = mu;
        srs = rsqrtf(var + 1e-5f);
    }
    __syncthreads();
    const float mu = smu, rs = srs;
    float2 gv = ((const float2*)g)[t];
    float2 bv = ((const float2*)bvec)[t];
    float2 o;
    o.x = (a - mu) * rs * gv.x + bv.x;
    o.y = (c - mu) * rs * gv.y + bv.y;
    ((float2*)(out + (size_t)row * DMODEL))[t] = o;
}

extern "C" void kernel_launch(void* const* d_in, const int* in_sizes, int n_in,
                              void* d_out, int out_size, void* d_ws, size_t ws_size,
                              hipStream_t stream)
{
    const float* q    = (const float*)d_in[0];
    const float* k    = (const float*)d_in[1];
    const float* v    = (const float*)d_in[2];
    const int*   mask = (const int*)d_in[3];
    const int*   tf1  = (const int*)d_in[4];
    const int*   tf2  = (const int*)d_in[5];
    const int*   tf3  = (const int*)d_in[6];
    const int*   tf4  = (const int*)d_in[7];
    const int*   tf5  = (const int*)d_in[8];
    const float* w_q  = (const float*)d_in[9];
    const float* b_q  = (const float*)d_in[10];
    const float* w_k  = (const float*)d_in[11];
    const float* b_k  = (const float*)d_in[12];
    const float* w_v  = (const float*)d_in[13];
    const float* b_v  = (const float*)d_in[14];
    const float* emb1 = (const float*)d_in[15];
    const float* emb2 = (const float*)d_in[16];
    const float* emb3 = (const float*)d_in[17];
    const float* emb4 = (const float*)d_in[18];
    const float* emb5 = (const float*)d_in[19];
    const float* fc_w = (const float*)d_in[20];
    const float* fc_b = (const float*)d_in[21];
    const float* ln_g = (const float*)d_in[22];
    const float* ln_b = (const float*)d_in[23];

    float* out  = (float*)d_out;                       // [2048][512]
    float* attn = out + (size_t)NB * L_SEQ * DMODEL;   // [16][1024][1024]

    // ws layout (bytes): total 18 MiB of the 20 MiB workspace
    char* wsb = (char*)d_ws;
    unsigned* pk = (unsigned*)(wsb + 0);                // 8 MiB [2][1024][1024] u32
    short* Wtq  = (short*)(wsb + (8u << 20));           // 0.5 MiB [512n][512k]
    short* Wtk  = (short*)(wsb + (8u << 20) + (512u << 10));
    short* Wtv  = (short*)(wsb + (9u << 20));
    short* Wtfc = (short*)(wsb + (9u << 20) + (512u << 10));
    short* qh   = (short*)(wsb + (10u << 20));          // 2 MiB [2048][512] bf16
    short* kh   = (short*)(wsb + (12u << 20));          // 2 MiB
    short* vht  = (short*)(wsb + (14u << 20));          // 2 MiB [2][512][1024] bf16
    short* pv   = (short*)(wsb + (16u << 20));          // 2 MiB [2048][512] bf16

    const int npk4 = NB * L_SEQ * L_SEQ / 4;            // 524288

    pack_tf_kernel<<<npk4 / 256, 256, 0, stream>>>(
        mask, tf1, tf2, tf3, tf4, tf5, pk, npk4);

    transpose_cast_kernel<<<dim3(16, 16, 4), dim3(32, 8), 0, stream>>>(
        w_q, w_k, w_v, fc_w, Wtq, Wtk, Wtv, Wtfc);

    proj_gemm_kernel<<<dim3(16, 64, 3), 128, 0, stream>>>(
        q, k, v, Wtq, Wtk, Wtv, b_q, b_k, b_v, qh, kh, vht);

    ssm_kernel<<<dim3(16, 64), 256, 0, stream>>>(
        qh, kh, pk, emb1, emb2, emb3, emb4, emb5, attn);

    av_mfma_kernel<<<dim3(64, 16), 256, 0, stream>>>(attn, vht, pv);

    fc_gemm_kernel<<<dim3(16, 64), 128, 0, stream>>>(pv, Wtfc, fc_b, out);

    ln_kernel<<<NB * L_SEQ, 256, 0, stream>>>(out, q, ln_g, ln_b, out);
}

// Round 5
// 277.931 us; speedup vs baseline: 1.0819x; 1.0006x over previous
//
#include <hip/hip_runtime.h>
#include <math.h>

#define L_SEQ 1024
#define DMODEL 512
#define NHEAD 8
#define NB 2

typedef __attribute__((ext_vector_type(8))) short bf8;
typedef __attribute__((ext_vector_type(4))) float f4;

__device__ __forceinline__ short f2bf(float f) {
    unsigned u = __float_as_uint(f);
    unsigned r = u + 0x7FFF + ((u >> 16) & 1);   // round-to-nearest-even
    return (short)(r >> 16);
}

// ---------------------------------------------------------------------------
// pack mask + tf1..5 into one u32 per (b,l,m):
// bit31 = mask, bits24-30 = tf1+1 (0 => padding), 18-23 = tf2, 12-17 = tf3,
// 6-11 = tf4, 0-5 = tf5
// ---------------------------------------------------------------------------
__global__ __launch_bounds__(256) void pack_tf_kernel(
    const int* __restrict__ mask,
    const int* __restrict__ tf1, const int* __restrict__ tf2,
    const int* __restrict__ tf3, const int* __restrict__ tf4,
    const int* __restrict__ tf5, unsigned* __restrict__ pk, int n4)
{
    int i = blockIdx.x * 256 + threadIdx.x;
    if (i >= n4) return;
    const int4 mk = ((const int4*)mask)[i];
    const int4 a1 = ((const int4*)tf1)[i];
    const int4 a2 = ((const int4*)tf2)[i];
    const int4 a3 = ((const int4*)tf3)[i];
    const int4 a4 = ((const int4*)tf4)[i];
    const int4 a5 = ((const int4*)tf5)[i];
    uint4 o;
#define PK(F) ((mk.F ? 0x80000000u : 0u) | ((unsigned)(a1.F + 1) << 24) \
               | ((unsigned)a2.F << 18) | ((unsigned)a3.F << 12)        \
               | ((unsigned)a4.F << 6) | (unsigned)a5.F)
    o.x = PK(x); o.y = PK(y); o.z = PK(z); o.w = PK(w);
#undef PK
    ((uint4*)pk)[i] = o;
}

// ---------------------------------------------------------------------------
// 512x512 fp32 W[k][n] -> bf16 Wt[n][k], 4 matrices via blockIdx.z
// ---------------------------------------------------------------------------
__global__ __launch_bounds__(256) void transpose_cast_kernel(
    const float* __restrict__ s0, const float* __restrict__ s1,
    const float* __restrict__ s2, const float* __restrict__ s3,
    short* __restrict__ d0, short* __restrict__ d1,
    short* __restrict__ d2, short* __restrict__ d3)
{
    const float* src; short* dst;
    switch (blockIdx.z) {
        case 0: src = s0; dst = d0; break;
        case 1: src = s1; dst = d1; break;
        case 2: src = s2; dst = d2; break;
        default: src = s3; dst = d3; break;
    }
    __shared__ float tile[32][33];
    const int tx = threadIdx.x, ty = threadIdx.y;
    const int x0 = blockIdx.x * 32, y0 = blockIdx.y * 32;
#pragma unroll
    for (int j = 0; j < 32; j += 8)
        tile[ty + j][tx] = src[(size_t)(y0 + ty + j) * 512 + x0 + tx];
    __syncthreads();
#pragma unroll
    for (int j = 0; j < 32; j += 8)
        dst[(size_t)(x0 + ty + j) * 512 + y0 + tx] = f2bf(tile[tx][ty + j]);
}

// ---------------------------------------------------------------------------
// Projection GEMMs, all 3 in one launch (z = 0:q, 1:k, 2:v).
// A read directly as fp32, converted to bf16 in-register.
// z<2 writes natural bf16 [m][512]; z==2 writes vht[b][n][l] transposed.
// ---------------------------------------------------------------------------
__global__ __launch_bounds__(128) void proj_gemm_kernel(
    const float* __restrict__ q, const float* __restrict__ k,
    const float* __restrict__ v,
    const short* __restrict__ Wtq, const short* __restrict__ Wtk,
    const short* __restrict__ Wtv,
    const float* __restrict__ b_q, const float* __restrict__ b_k,
    const float* __restrict__ b_v,
    short* __restrict__ qh, short* __restrict__ kh, short* __restrict__ vht)
{
    const int z = blockIdx.z;
    const float* A    = (z == 0) ? q   : (z == 1) ? k   : v;
    const short* Bt   = (z == 0) ? Wtq : (z == 1) ? Wtk : Wtv;
    const float* bias = (z == 0) ? b_q : (z == 1) ? b_k : b_v;

    const int w = threadIdx.x >> 6, lane = threadIdx.x & 63;
    const int lr = lane & 15, lq = lane >> 4;
    const int m_base = blockIdx.y * 32 + w * 16;
    const int n_base = blockIdx.x * 32;

    f4 acc[2];
    const f4 zero = {0.f, 0.f, 0.f, 0.f};
    acc[0] = zero; acc[1] = zero;

    for (int k0 = 0; k0 < 512; k0 += 32) {
        const float* p = A + (size_t)(m_base + lr) * 512 + k0 + lq * 8;
        float4 f0 = *(const float4*)p;
        float4 f1 = *(const float4*)(p + 4);
        bf8 a;
        a[0] = f2bf(f0.x); a[1] = f2bf(f0.y); a[2] = f2bf(f0.z); a[3] = f2bf(f0.w);
        a[4] = f2bf(f1.x); a[5] = f2bf(f1.y); a[6] = f2bf(f1.z); a[7] = f2bf(f1.w);
#pragma unroll
        for (int nf = 0; nf < 2; ++nf) {
            bf8 b = *(const bf8*)(Bt + (size_t)(n_base + nf * 16 + lr) * 512 + k0 + lq * 8);
            acc[nf] = __builtin_amdgcn_mfma_f32_16x16x32_bf16(a, b, acc[nf], 0, 0, 0);
        }
    }

    short* Cnat = (z == 0) ? qh : kh;
#pragma unroll
    for (int nf = 0; nf < 2; ++nf) {
        const int n = n_base + nf * 16 + lr;
        const float bv = bias[n];
        const int mrow = m_base + lq * 4;
#pragma unroll
        for (int r = 0; r < 4; ++r) {
            const float val = acc[nf][r] + bv;
            const int m = mrow + r;
            if (z < 2) {
                Cnat[(size_t)m * 512 + n] = f2bf(val);
            } else {
                const int bb = m >> 10, l = m & 1023;
                vht[((size_t)bb * 512 + n) * 1024 + l] = f2bf(val);
            }
        }
    }
}

// ---------------------------------------------------------------------------
// Fused scores + bias + mask + softmax (single pass), writes normalized attn.
// Block = (z, 16 q-rows), 512 thr = 8 waves; wave w owns m-range w*128.
// Per-wave S state sv[8][4] = 32 VGPR (register-resident, no spill).
// S mapping + pk bias fold identical to the verified R4 kernel.
// ---------------------------------------------------------------------------
__global__ __launch_bounds__(512, 2) void ssm_kernel(
    const short* __restrict__ qh, const short* __restrict__ kh,
    const unsigned* __restrict__ pk,
    const float* __restrict__ emb1, const float* __restrict__ emb2,
    const float* __restrict__ emb3, const float* __restrict__ emb4,
    const float* __restrict__ emb5,
    float* __restrict__ attn)
{
    const int z = blockIdx.x, h = z >> 1, b = z & 1;
    const int t = threadIdx.x;
    const int wave = t >> 6, lane = t & 63;
    const int lr = lane & 15, lq = lane >> 4;
    const int l0 = blockIdx.y * 16;
    const int mbase = wave * 128;

    __shared__ float embs[5][64];
    __shared__ float red_mx[8][16];
    __shared__ float red_sm[8][16];

    if (t < 320) {
        const float* es[5] = {emb1, emb2, emb3, emb4, emb5};
        embs[t >> 6][t & 63] = es[t >> 6][(t & 63) * NHEAD + h];
    }

    // Q fragments (A-operand: lane lr = row, lq*8 = k offset) — loaded once
    const short* qp = qh + ((size_t)(b * L_SEQ + l0 + lr)) * DMODEL + h * 64 + lq * 8;
    const bf8 aq0 = *(const bf8*)qp;
    const bf8 aq1 = *(const bf8*)(qp + 32);

    const int lrow0 = l0 + lq * 4;           // first of this lane's 4 C/D rows
    int tboff[4];
#pragma unroll
    for (int r = 0; r < 4; ++r)
        tboff[r] = (b * L_SEQ + lrow0 + r) * L_SEQ + lr;
    const short* kbp = kh + (size_t)b * L_SEQ * DMODEL + h * 64 + lq * 8;

    __syncthreads();

    const f4 zero = {0.f, 0.f, 0.f, 0.f};

    // ---- compute raw S for the 8 m-tiles of this wave's 128-wide range ----
    float sv[8][4];
#pragma unroll
    for (int tile = 0; tile < 8; ++tile) {
        const int m0 = mbase + tile * 16;
        f4 acc = zero;
        const short* kp = kbp + (size_t)(m0 + lr) * DMODEL;
        const bf8 b0 = *(const bf8*)kp;
        const bf8 b1 = *(const bf8*)(kp + 32);
        acc = __builtin_amdgcn_mfma_f32_16x16x32_bf16(aq0, b0, acc, 0, 0, 0);
        acc = __builtin_amdgcn_mfma_f32_16x16x32_bf16(aq1, b1, acc, 0, 0, 0);
#pragma unroll
        for (int r = 0; r < 4; ++r) {
            const unsigned u = pk[tboff[r] + m0];
            float sval;
            if (u & 0x80000000u) { sval = -INFINITY; }
            else {
                const int i1m = (u >> 24) & 0x7F;
                float bs = 0.f;
                if (i1m) bs = embs[0][i1m - 1] + embs[1][(u >> 18) & 63]
                            + embs[2][(u >> 12) & 63]
                            + embs[3][(u >> 6) & 63] + embs[4][u & 63];
                sval = (acc[r] + bs) * 0.125f;
            }
            sv[tile][r] = sval;
        }
    }

    // ---- per-row max: in-lane over tiles -> 16-lane shfl -> cross-wave LDS ----
    float mx[4];
#pragma unroll
    for (int r = 0; r < 4; ++r) mx[r] = -INFINITY;
#pragma unroll
    for (int tile = 0; tile < 8; ++tile)
#pragma unroll
        for (int r = 0; r < 4; ++r) mx[r] = fmaxf(mx[r], sv[tile][r]);
#pragma unroll
    for (int r = 0; r < 4; ++r) {
#pragma unroll
        for (int off = 1; off < 16; off <<= 1)
            mx[r] = fmaxf(mx[r], __shfl_xor(mx[r], off));
    }
    if (lr == 0) {
#pragma unroll
        for (int r = 0; r < 4; ++r) red_mx[wave][lq * 4 + r] = mx[r];
    }
    __syncthreads();

    float mf[4];
#pragma unroll
    for (int r = 0; r < 4; ++r) {
        const int row = lq * 4 + r;
        float m01 = fmaxf(red_mx[0][row], red_mx[1][row]);
        float m23 = fmaxf(red_mx[2][row], red_mx[3][row]);
        float m45 = fmaxf(red_mx[4][row], red_mx[5][row]);
        float m67 = fmaxf(red_mx[6][row], red_mx[7][row]);
        mf[r] = fmaxf(fmaxf(m01, m23), fmaxf(m45, m67));
    }

    // ---- exp (once) + per-row sum ----
    float sm[4] = {0.f, 0.f, 0.f, 0.f};
#pragma unroll
    for (int tile = 0; tile < 8; ++tile) {
#pragma unroll
        for (int r = 0; r < 4; ++r) {
            const float e = (sv[tile][r] > -INFINITY) ? __expf(sv[tile][r] - mf[r]) : 0.f;
            sv[tile][r] = e;
            sm[r] += e;
        }
    }
#pragma unroll
    for (int r = 0; r < 4; ++r) {
#pragma unroll
        for (int off = 1; off < 16; off <<= 1)
            sm[r] += __shfl_xor(sm[r], off);
    }
    if (lr == 0) {
#pragma unroll
        for (int r = 0; r < 4; ++r) red_sm[wave][lq * 4 + r] = sm[r];
    }
    __syncthreads();

    float inv[4];
#pragma unroll
    for (int r = 0; r < 4; ++r) {
        const int row = lq * 4 + r;
        const float s = ((red_sm[0][row] + red_sm[1][row])
                       + (red_sm[2][row] + red_sm[3][row]))
                      + ((red_sm[4][row] + red_sm[5][row])
                       + (red_sm[6][row] + red_sm[7][row]));
        inv[r] = (s > 0.f) ? 1.0f / s : 0.f;
    }

    // ---- normalize + write attn ----
    float* ap = attn + (size_t)z * L_SEQ * L_SEQ;
#pragma unroll
    for (int tile = 0; tile < 8; ++tile) {
#pragma unroll
        for (int r = 0; r < 4; ++r)
            ap[(size_t)(lrow0 + r) * L_SEQ + mbase + tile * 16 + lr] = sv[tile][r] * inv[r];
    }
}

// ---------------------------------------------------------------------------
// AV GEMM, split-K: per z=h*2+b, pv[b,l,h*64+d] = sum_m attn[z,l,m]*vht[b,h*64+d,m]
// Block = 16 rows x 64 d; each of 4 waves owns a 256-wide K-quarter, then
// cross-wave LDS reduce (wave w finalizes cols w*16..w*16+15).
// ---------------------------------------------------------------------------
__global__ __launch_bounds__(256) void av_mfma_kernel(
    const float* __restrict__ attn, const short* __restrict__ vht,
    short* __restrict__ pv)
{
    const int z = blockIdx.y, h = z >> 1, b = z & 1;
    const int w = threadIdx.x >> 6, lane = threadIdx.x & 63;
    const int lr = lane & 15, lq = lane >> 4;
    const int l0 = blockIdx.x * 16;
    const float* Ab = attn + (size_t)z * L_SEQ * L_SEQ;
    const short* Bb = vht + ((size_t)b * 512 + h * 64) * 1024;

    f4 acc[4];
    const f4 zero = {0.f, 0.f, 0.f, 0.f};
#pragma unroll
    for (int nt = 0; nt < 4; ++nt) acc[nt] = zero;

    const int kbeg = w * 256;
    for (int k0 = kbeg; k0 < kbeg + 256; k0 += 32) {
        const float* p = Ab + (size_t)(l0 + lr) * 1024 + k0 + lq * 8;
        float4 f0 = *(const float4*)p;
        float4 f1 = *(const float4*)(p + 4);
        bf8 a;
        a[0] = f2bf(f0.x); a[1] = f2bf(f0.y); a[2] = f2bf(f0.z); a[3] = f2bf(f0.w);
        a[4] = f2bf(f1.x); a[5] = f2bf(f1.y); a[6] = f2bf(f1.z); a[7] = f2bf(f1.w);
#pragma unroll
        for (int nt = 0; nt < 4; ++nt) {
            bf8 bv = *(const bf8*)(Bb + (size_t)(nt * 16 + lr) * 1024 + k0 + lq * 8);
            acc[nt] = __builtin_amdgcn_mfma_f32_16x16x32_bf16(a, bv, acc[nt], 0, 0, 0);
        }
    }

    // cross-wave reduce: red[wave][nt][row][col], padded to 17 for bank spread
    __shared__ float red[4][4][16][17];
#pragma unroll
    for (int nt = 0; nt < 4; ++nt)
#pragma unroll
        for (int r = 0; r < 4; ++r)
            red[w][nt][lq * 4 + r][lr] = acc[nt][r];
    __syncthreads();

    // wave w finalizes n-frag nt == w
    f4 sum = zero;
#pragma unroll
    for (int j = 0; j < 4; ++j)
#pragma unroll
        for (int r = 0; r < 4; ++r)
            sum[r] += red[j][w][lq * 4 + r][lr];

#pragma unroll
    for (int r = 0; r < 4; ++r)
        pv[(size_t)(b * L_SEQ + l0 + lq * 4 + r) * 512 + h * 64 + w * 16 + lr] = f2bf(sum[r]);
}

// ---------------------------------------------------------------------------
// FC GEMM: C[m,n] = sum_k pv[m,k]*Wtfc[n,k] + fc_b[n], fp32 out (to d_out).
// ---------------------------------------------------------------------------
__global__ __launch_bounds__(128) void fc_gemm_kernel(
    const short* __restrict__ A, const short* __restrict__ Bt,
    const float* __restrict__ bias, float* __restrict__ Cout)
{
    const int w = threadIdx.x >> 6, lane = threadIdx.x & 63;
    const int lr = lane & 15, lq = lane >> 4;
    const int m_base = blockIdx.y * 32 + w * 16;
    const int n_base = blockIdx.x * 32;

    f4 acc[2];
    const f4 zero = {0.f, 0.f, 0.f, 0.f};
    acc[0] = zero; acc[1] = zero;

    for (int k0 = 0; k0 < 512; k0 += 32) {
        bf8 a = *(const bf8*)(A + (size_t)(m_base + lr) * 512 + k0 + lq * 8);
#pragma unroll
        for (int nf = 0; nf < 2; ++nf) {
            bf8 b = *(const bf8*)(Bt + (size_t)(n_base + nf * 16 + lr) * 512 + k0 + lq * 8);
            acc[nf] = __builtin_amdgcn_mfma_f32_16x16x32_bf16(a, b, acc[nf], 0, 0, 0);
        }
    }

#pragma unroll
    for (int nf = 0; nf < 2; ++nf) {
        const int n = n_base + nf * 16 + lr;
        const float bv = bias[n];
        const int mrow = m_base + lq * 4;
#pragma unroll
        for (int r = 0; r < 4; ++r)
            Cout[(size_t)(mrow + r) * 512 + n] = acc[nf][r] + bv;
    }
}

// ---------------------------------------------------------------------------
// residual add + LayerNorm, one block per row, in-place on x(=out)
// ---------------------------------------------------------------------------
__global__ __launch_bounds__(256) void ln_kernel(
    const float* __restrict__ x, const float* __restrict__ res,
    const float* __restrict__ g, const float* __restrict__ bvec,
    float* __restrict__ out)
{
    const int row = blockIdx.x;
    const int t = threadIdx.x;
    float2 xv = ((const float2*)(x + (size_t)row * DMODEL))[t];
    float2 rv = ((const float2*)(res + (size_t)row * DMODEL))[t];
    const float a = xv.x + rv.x;
    const float c = xv.y + rv.y;
    float s = a + c, sq = a * a + c * c;
#pragma unroll
    for (int off = 32; off; off >>= 1) {
        s  += __shfl_down(s, off);
        sq += __shfl_down(sq, off);
    }
    __shared__ float ssum[4], ssq[4];
    __shared__ float smu, srs;
    const int wid = t >> 6, lane = t & 63;
    if (lane == 0) { ssum[wid] = s; ssq[wid] = sq; }
    __syncthreads();
    if (t == 0) {
        float ts = ssum[0] + ssum[1] + ssum[2] + ssum[3];
        float tq = ssq[0] + ssq[1] + ssq[2] + ssq[3];
        float mu = ts * (1.0f / DMODEL);
        float var = tq * (1.0f / DMODEL) - mu * mu;
        smu = mu;
        srs = rsqrtf(var + 1e-5f);
    }
    __syncthreads();
    const float mu = smu, rs = srs;
    float2 gv = ((const float2*)g)[t];
    float2 bv = ((const float2*)bvec)[t];
    float2 o;
    o.x = (a - mu) * rs * gv.x + bv.x;
    o.y = (c - mu) * rs * gv.y + bv.y;
    ((float2*)(out + (size_t)row * DMODEL))[t] = o;
}

extern "C" void kernel_launch(void* const* d_in, const int* in_sizes, int n_in,
                              void* d_out, int out_size, void* d_ws, size_t ws_size,
                              hipStream_t stream)
{
    const float* q    = (const float*)d_in[0];
    const float* k    = (const float*)d_in[1];
    const float* v    = (const float*)d_in[2];
    const int*   mask = (const int*)d_in[3];
    const int*   tf1  = (const int*)d_in[4];
    const int*   tf2  = (const int*)d_in[5];
    const int*   tf3  = (const int*)d_in[6];
    const int*   tf4  = (const int*)d_in[7];
    const int*   tf5  = (const int*)d_in[8];
    const float* w_q  = (const float*)d_in[9];
    const float* b_q  = (const float*)d_in[10];
    const float* w_k  = (const float*)d_in[11];
    const float* b_k  = (const float*)d_in[12];
    const float* w_v  = (const float*)d_in[13];
    const float* b_v  = (const float*)d_in[14];
    const float* emb1 = (const float*)d_in[15];
    const float* emb2 = (const float*)d_in[16];
    const float* emb3 = (const float*)d_in[17];
    const float* emb4 = (const float*)d_in[18];
    const float* emb5 = (const float*)d_in[19];
    const float* fc_w = (const float*)d_in[20];
    const float* fc_b = (const float*)d_in[21];
    const float* ln_g = (const float*)d_in[22];
    const float* ln_b = (const float*)d_in[23];

    float* out  = (float*)d_out;                       // [2048][512]
    float* attn = out + (size_t)NB * L_SEQ * DMODEL;   // [16][1024][1024]

    // ws layout (bytes): total 18 MiB of the 20 MiB workspace
    char* wsb = (char*)d_ws;
    unsigned* pk = (unsigned*)(wsb + 0);                // 8 MiB [2][1024][1024] u32
    short* Wtq  = (short*)(wsb + (8u << 20));           // 0.5 MiB [512n][512k]
    short* Wtk  = (short*)(wsb + (8u << 20) + (512u << 10));
    short* Wtv  = (short*)(wsb + (9u << 20));
    short* Wtfc = (short*)(wsb + (9u << 20) + (512u << 10));
    short* qh   = (short*)(wsb + (10u << 20));          // 2 MiB [2048][512] bf16
    short* kh   = (short*)(wsb + (12u << 20));          // 2 MiB
    short* vht  = (short*)(wsb + (14u << 20));          // 2 MiB [2][512][1024] bf16
    short* pv   = (short*)(wsb + (16u << 20));          // 2 MiB [2048][512] bf16

    const int npk4 = NB * L_SEQ * L_SEQ / 4;            // 524288

    pack_tf_kernel<<<npk4 / 256, 256, 0, stream>>>(
        mask, tf1, tf2, tf3, tf4, tf5, pk, npk4);

    transpose_cast_kernel<<<dim3(16, 16, 4), dim3(32, 8), 0, stream>>>(
        w_q, w_k, w_v, fc_w, Wtq, Wtk, Wtv, Wtfc);

    proj_gemm_kernel<<<dim3(16, 64, 3), 128, 0, stream>>>(
        q, k, v, Wtq, Wtk, Wtv, b_q, b_k, b_v, qh, kh, vht);

    ssm_kernel<<<dim3(16, 64), 512, 0, stream>>>(
        qh, kh, pk, emb1, emb2, emb3, emb4, emb5, attn);

    av_mfma_kernel<<<dim3(64, 16), 256, 0, stream>>>(attn, vht, pv);

    fc_gemm_kernel<<<dim3(16, 64), 128, 0, stream>>>(pv, Wtfc, fc_b, out);

    ln_kernel<<<NB * L_SEQ, 256, 0, stream>>>(out, q, ln_g, ln_b, out);
}